// Round 11
// baseline (1935.591 us; speedup 1.0000x reference)
//
#include <hip/hip_runtime.h>
#include <cstdint>
#include <cstddef>

#define NB 128
#define NC 16
#define NT 2048
#define NH 256
#define NG 1024
#define NO 10

typedef _Float16 f16;
typedef _Float16 h2 __attribute__((ext_vector_type(2)));
typedef _Float16 h8 __attribute__((ext_vector_type(8)));

static __device__ __forceinline__ float fdot2(h2 a, h2 b, float c) {
#if __has_builtin(__builtin_amdgcn_fdot2)
  return __builtin_amdgcn_fdot2(a, b, c, false);
#else
  return c + (float)a[0] * (float)b[0] + (float)a[1] * (float)b[1];
#endif
}

static __device__ __forceinline__ int sdot4(int a, int b, int c) {
#if __has_builtin(__builtin_amdgcn_sdot4)
  return __builtin_amdgcn_sdot4(a, b, c, false);
#else
  int r = c;
#pragma unroll
  for (int i = 0; i < 4; ++i)
    r += (int)(int8_t)(a >> (8 * i)) * (int)(int8_t)(b >> (8 * i));
  return r;
#endif
}

// VALU lane swap 2k<->2k+1 via DPP quad_perm [1,0,3,2] (no DS traffic).
static __device__ __forceinline__ float pairswap(float v) {
  int r = __builtin_amdgcn_update_dpp(0, __builtin_bit_cast(int, v),
                                      0xB1, 0xF, 0xF, true);
  return __builtin_bit_cast(float, r);
}

static __device__ __forceinline__ float sigm(float x) {
  return __builtin_amdgcn_rcpf(1.f + __expf(-x));
}

// Quantize w_hh (1024x256 f32 row-major) to i8 with per-row scale.
__global__ void prepack_whh_i8(const float* __restrict__ whh,
                               int8_t* __restrict__ wq,
                               float* __restrict__ scale) {
  int row = blockIdx.x;   // 0..1023
  int k   = threadIdx.x;  // 0..255
  float v = whh[row * NH + k];
  float m = fabsf(v);
  for (int off = 32; off; off >>= 1) m = fmaxf(m, __shfl_xor(m, off, 64));
  __shared__ float smax[4];
  if ((k & 63) == 0) smax[k >> 6] = m;
  __syncthreads();
  float mm = fmaxf(fmaxf(smax[0], smax[1]), fmaxf(smax[2], smax[3]));
  float s = fmaxf(mm, 1e-20f) / 127.f;
  int qv = (int)rintf(v / s);
  qv = min(127, max(-127, qv));
  wq[row * NH + k] = (int8_t)qv;
  if (k == 0) scale[row] = s;
}

// One workgroup per batch, 512 threads (8 waves -> 2 waves/SIMD).
// GATE-PARITY SPLIT: thread t = 2u+half owns hidden unit u; even lane
// computes gates (i,g) over the FULL k=256, odd lane computes (f,o).
// -> dot sums complete per lane (no k-reduction), h-reads are all-lane
// broadcast from ONE 256B copy per phase, trans per lane = 3 not 5
// (tanh via 2*sigm(2x)-1), tail exchange = 2 DPP swaps + 4 cndmask.
// All weight rows register-resident i8 (128 ints/lane). Exchanged gate
// values are bit-identical on both lanes -> redundant c can't diverge.
__global__ __launch_bounds__(512, 1)
void lstm_main(const float* __restrict__ x,
               const float* __restrict__ w_ih,
               const float* __restrict__ b_ih,
               const float* __restrict__ b_hh,
               const float* __restrict__ w_out,
               const float* __restrict__ b_out,
               const int8_t* __restrict__ wq,
               const float* __restrict__ scales,
               float* __restrict__ out) {
  const int t = threadIdx.x;   // 0..511
  const int u = t >> 1;        // hidden unit 0..255
  const int half = t & 1;      // gate-pair selector
  const int b = blockIdx.x;

  __shared__ __align__(16) int8_t hq8[2][NH];  // 512 B: h per phase (i8)
  __shared__ __align__(16) f16 xs[64][NC];     // 2 KB staged x
  __shared__ float hT[NH];
  __shared__ float lg[NO];

  // gate rows for this lane: A = (half? f : i), B = (half? o : g)
  const int rowA = (half ? 256 : 0) + u;
  const int rowB = (half ? 768 : 512) + u;

  // ---------------- one-time loads ----------------
  int wa_[64], wb_[64];  // 2 full gate rows (256 i8 each), packed i8x4
  h2 wihA[8], wihB[8];   // w_ih full rows (16 ch = 8 pairs) for A,B
  {
    const int4* pa = (const int4*)(wq + (size_t)rowA * NH);
    const int4* pb = (const int4*)(wq + (size_t)rowB * NH);
#pragma unroll
    for (int c = 0; c < 16; ++c) {
      int4 va = pa[c], vb = pb[c];
      wa_[4 * c + 0] = va.x; wa_[4 * c + 1] = va.y; wa_[4 * c + 2] = va.z; wa_[4 * c + 3] = va.w;
      wb_[4 * c + 0] = vb.x; wb_[4 * c + 1] = vb.y; wb_[4 * c + 2] = vb.z; wb_[4 * c + 3] = vb.w;
    }
  }
#pragma unroll
  for (int uu = 0; uu < 8; ++uu) {
    h2 ta = {(f16)w_ih[rowA * NC + 2 * uu], (f16)w_ih[rowA * NC + 2 * uu + 1]};
    h2 tb = {(f16)w_ih[rowB * NC + 2 * uu], (f16)w_ih[rowB * NC + 2 * uu + 1]};
    wihA[uu] = ta;
    wihB[uu] = tb;
  }
  const float K = 1.f / 127.f;
  const float scA = scales[rowA] * K;
  const float scB = scales[rowB] * K;
  const float bA = b_ih[rowA] + b_hh[rowA];
  const float bB = b_ih[rowB] + b_hh[rowB];

  // zero h (both phases), stage x chunk 0
  if (t < 2 * NH) hq8[0][t] = 0;  // covers both phases (2*256 = 512 = blockDim)
  {
    int cc = t >> 6, tt = t & 63;  // wait: 512 threads, 1024 elems -> 2 per
  }
#pragma unroll
  for (int r = 0; r < 2; ++r) {
    int e = t + 512 * r;  // 0..1023 over (c, tt)
    int cc = e >> 6, tt = e & 63;
    xs[tt][cc] = (f16)x[(size_t)(b * NC + cc) * NT + tt];
  }
  __syncthreads();

  // ---------------- recurrence ----------------
  float c_ = 0.f, h_last = 0.f;

#pragma unroll 1
  for (int s = 0; s < NT; ++s) {
    const int p = s & 1;
    const int4* hrd = (const int4*)&hq8[p][0];  // same addr ALL lanes: broadcast

    // x projection for this lane's two gates (full 16 channels)
    float xa = bA, xb = bB;
    {
      const h8* xr = (const h8*)&xs[s & 63][0];
      h8 x0 = xr[0], x1 = xr[1];
#pragma unroll
      for (int uu = 0; uu < 4; ++uu) {
        h2 xp0 = {x0[2 * uu], x0[2 * uu + 1]};
        h2 xp1 = {x1[2 * uu], x1[2 * uu + 1]};
        xa = fdot2(xp0, wihA[uu], xa);
        xa = fdot2(xp1, wihA[uu + 4], xa);
        xb = fdot2(xp0, wihB[uu], xb);
        xb = fdot2(xp1, wihB[uu + 4], xb);
      }
    }

    // full-k recurrent dots for gates A and B (2 chains each for ILP)
    int a0 = 0, a0b = 0, b0 = 0, b0b = 0;
#pragma unroll
    for (int c = 0; c < 8; ++c) {
      int4 h0 = hrd[2 * c];
      int4 h1 = hrd[2 * c + 1];
      a0 = sdot4(h0.x, wa_[8 * c + 0], a0); a0 = sdot4(h0.y, wa_[8 * c + 1], a0);
      a0 = sdot4(h0.z, wa_[8 * c + 2], a0); a0 = sdot4(h0.w, wa_[8 * c + 3], a0);
      a0b = sdot4(h1.x, wa_[8 * c + 4], a0b); a0b = sdot4(h1.y, wa_[8 * c + 5], a0b);
      a0b = sdot4(h1.z, wa_[8 * c + 6], a0b); a0b = sdot4(h1.w, wa_[8 * c + 7], a0b);
      b0 = sdot4(h0.x, wb_[8 * c + 0], b0); b0 = sdot4(h0.y, wb_[8 * c + 1], b0);
      b0 = sdot4(h0.z, wb_[8 * c + 2], b0); b0 = sdot4(h0.w, wb_[8 * c + 3], b0);
      b0b = sdot4(h1.x, wb_[8 * c + 4], b0b); b0b = sdot4(h1.y, wb_[8 * c + 5], b0b);
      b0b = sdot4(h1.z, wb_[8 * c + 6], b0b); b0b = sdot4(h1.w, wb_[8 * c + 7], b0b);
    }

    // dequant (+x-proj, bias): complete gate pre-activations per lane
    float va = xa + (float)(a0 + a0b) * scA;  // even: i | odd: f
    float vb = xb + (float)(b0 + b0b) * scB;  // even: g | odd: o

    // activations: A-gate is sigmoid on both parities; B-gate is tanh on
    // even (g), sigmoid on odd (o). tanh(x) = 2*sigm(2x)-1.
    float ta = sigm(va);
    float argb = half ? vb : 2.f * vb;
    float sb = sigm(argb);
    float tb = half ? sb : 2.f * sb - 1.f;

    // exchange across the pair (bit-identical both lanes)
    float ea = pairswap(ta);  // even: sigm(f) | odd: sigm(i)
    float eb = pairswap(tb);  // even: sigm(o) | odd: tanh(g)
    float ig = half ? ea : ta;
    float fg = half ? ta : ea;
    float gv = half ? eb : tb;
    float og = half ? tb : eb;

    c_ = fg * c_ + ig * gv;
    float tc = sigm(2.f * c_);
    float hh = og * (2.f * tc - 1.f);
    h_last = hh;
    // quantize h (|hh| < 1); even lane writes the single copy
    if (!half) hq8[1 - p][u] = (int8_t)(int)rintf(hh * 127.f);

    // restage x every 64 steps (extra barrier protects WAR on xs)
    if ((s & 63) == 63 && s != NT - 1) {
      __syncthreads();
#pragma unroll
      for (int r = 0; r < 2; ++r) {
        int e = t + 512 * r;
        int cc = e >> 6, tt = e & 63;
        xs[tt][cc] = (f16)x[(size_t)(b * NC + cc) * NT + (s + 1) + tt];
      }
    }
    __syncthreads();
  }

  // ---------------- head: logits + log_softmax ----------------
  if (!half) hT[u] = h_last;
  __syncthreads();
  if (t < NO) {
    float acc = b_out[t];
    for (int k = 0; k < NH; ++k) acc += hT[k] * w_out[t * NH + k];
    lg[t] = acc;
  }
  __syncthreads();
  if (t == 0) {
    float m = lg[0];
    for (int o = 1; o < NO; ++o) m = fmaxf(m, lg[o]);
    float ssum = 0.f;
    for (int o = 0; o < NO; ++o) ssum += __expf(lg[o] - m);
    float lse = m + __logf(ssum);
    for (int o = 0; o < NO; ++o) out[b * NO + o] = lg[o] - lse;
  }
}

extern "C" void kernel_launch(void* const* d_in, const int* in_sizes, int n_in,
                              void* d_out, int out_size, void* d_ws, size_t ws_size,
                              hipStream_t stream) {
  const float* x    = (const float*)d_in[0];
  const float* wih  = (const float*)d_in[1];
  const float* whh  = (const float*)d_in[2];
  const float* bih  = (const float*)d_in[3];
  const float* bhh  = (const float*)d_in[4];
  const float* wout = (const float*)d_in[5];
  const float* bout = (const float*)d_in[6];
  float* out = (float*)d_out;
  int8_t* wq = (int8_t*)d_ws;                       // 256 KB i8 w_hh
  float* scales = (float*)((char*)d_ws + NG * NH);  // 4 KB row scales

  hipLaunchKernelGGL(prepack_whh_i8, dim3(NG), dim3(NH), 0, stream, whh, wq, scales);
  hipLaunchKernelGGL(lstm_main, dim3(NB), dim3(512), 0, stream,
                     x, wih, bih, bhh, wout, bout, wq, scales, out);
}

// Round 12
// 1816.678 us; speedup vs baseline: 1.0655x; 1.0655x over previous
//
#include <hip/hip_runtime.h>
#include <cstdint>
#include <cstddef>

#define NB 128
#define NC 16
#define NT 2048
#define NH 256
#define NG 1024
#define NO 10

typedef _Float16 f16;
typedef _Float16 h2 __attribute__((ext_vector_type(2)));
typedef _Float16 h8 __attribute__((ext_vector_type(8)));

// h state: i8[256] per phase, TWO bank-offset copies per phase.
//   phase stride 544 B, copy offsets {0, 272}.
// Reads (int4): half0 at 544p + 16c -> banks {4c..4c+3}; half1 at
// 544p + 400 + 16c -> banks {4c+4..4c+7} -> bank-disjoint per instruction.
#define HPHASE 544

static __device__ __forceinline__ float fdot2(h2 a, h2 b, float c) {
#if __has_builtin(__builtin_amdgcn_fdot2)
  return __builtin_amdgcn_fdot2(a, b, c, false);
#else
  return c + (float)a[0] * (float)b[0] + (float)a[1] * (float)b[1];
#endif
}

static __device__ __forceinline__ int sdot4(int a, int b, int c) {
#if __has_builtin(__builtin_amdgcn_sdot4)
  return __builtin_amdgcn_sdot4(a, b, c, false);
#else
  int r = c;
#pragma unroll
  for (int i = 0; i < 4; ++i)
    r += (int)(int8_t)(a >> (8 * i)) * (int)(int8_t)(b >> (8 * i));
  return r;
#endif
}

// VALU lane swap 2k<->2k+1 via DPP quad_perm [1,0,3,2] (no DS traffic).
static __device__ __forceinline__ float pairswap(float v) {
  int r = __builtin_amdgcn_update_dpp(0, __builtin_bit_cast(int, v),
                                      0xB1, 0xF, 0xF, true);
  return __builtin_bit_cast(float, r);
}

static __device__ __forceinline__ float sigm(float x) {
  return __builtin_amdgcn_rcpf(1.f + __expf(-x));
}
static __device__ __forceinline__ float tanh_(float x) {
  return 1.f - 2.f * __builtin_amdgcn_rcpf(1.f + __expf(2.f * x));
}

// Quantize w_hh (1024x256 f32 row-major) to i8 with per-row scale.
__global__ void prepack_whh_i8(const float* __restrict__ whh,
                               int8_t* __restrict__ wq,
                               float* __restrict__ scale) {
  int row = blockIdx.x;   // 0..1023
  int k   = threadIdx.x;  // 0..255
  float v = whh[row * NH + k];
  float m = fabsf(v);
  for (int off = 32; off; off >>= 1) m = fmaxf(m, __shfl_xor(m, off, 64));
  __shared__ float smax[4];
  if ((k & 63) == 0) smax[k >> 6] = m;
  __syncthreads();
  float mm = fmaxf(fmaxf(smax[0], smax[1]), fmaxf(smax[2], smax[3]));
  float s = fmaxf(mm, 1e-20f) / 127.f;
  int qv = (int)rintf(v / s);
  qv = min(127, max(-127, qv));
  wq[row * NH + k] = (int8_t)qv;
  if (k == 0) scale[row] = s;
}

// One workgroup per batch, 512 threads (8 waves -> 2 waves/SIMD, 256-reg
// unified budget). Thread t = 2u+half: hidden unit u, k-half `half`
// (128 wide). All 4 i8 gate half-rows register-resident (128 ints).
// h is i8 in 2 bank-offset LDS copies (bank-disjoint reads and writes).
// v_dot4_i32_i8 -> i32, dequant by scale[row]/127, DPP pair-reduce (f32,
// bit-identical on both lanes so the redundant cell state can't diverge).
// [R8-R11 post-mortems: hv-hoist, x-proj pipelining, LDS weight
// streaming, and gate-parity splits are all neutral-to-worse; this shape
// is the measured optimum of the family.]
__global__ __launch_bounds__(512, 1)
void lstm_main(const float* __restrict__ x,
               const float* __restrict__ w_ih,
               const float* __restrict__ b_ih,
               const float* __restrict__ b_hh,
               const float* __restrict__ w_out,
               const float* __restrict__ b_out,
               const int8_t* __restrict__ wq,
               const float* __restrict__ scales,
               float* __restrict__ out) {
  const int t = threadIdx.x;   // 0..511
  const int u = t >> 1;        // hidden unit 0..255
  const int half = t & 1;      // k-half
  const int b = blockIdx.x;

  __shared__ __align__(16) int8_t hq8[2 * HPHASE];  // 1.1 KB h copies
  __shared__ __align__(16) f16 xs[64][NC];          // 2 KB staged x
  __shared__ float hT[NH];
  __shared__ float lg[NO];

  // ---------------- one-time loads ----------------
  int wi_[32], wf_[32], wg_[32], wo_[32];  // 4 gate half-rows, packed i8x4
  h2 wih[4][4];                            // w_ih half-rows (8 ch) x 4 gates
  {
    const int4* pi = (const int4*)(wq + (size_t)u * NH + 128 * half);
    const int4* pf = (const int4*)(wq + (size_t)(256 + u) * NH + 128 * half);
    const int4* pg = (const int4*)(wq + (size_t)(512 + u) * NH + 128 * half);
    const int4* po = (const int4*)(wq + (size_t)(768 + u) * NH + 128 * half);
#pragma unroll
    for (int c = 0; c < 8; ++c) {
      int4 vi = pi[c], vf = pf[c], vg = pg[c], vo = po[c];
      wi_[4 * c + 0] = vi.x; wi_[4 * c + 1] = vi.y; wi_[4 * c + 2] = vi.z; wi_[4 * c + 3] = vi.w;
      wf_[4 * c + 0] = vf.x; wf_[4 * c + 1] = vf.y; wf_[4 * c + 2] = vf.z; wf_[4 * c + 3] = vf.w;
      wg_[4 * c + 0] = vg.x; wg_[4 * c + 1] = vg.y; wg_[4 * c + 2] = vg.z; wg_[4 * c + 3] = vg.w;
      wo_[4 * c + 0] = vo.x; wo_[4 * c + 1] = vo.y; wo_[4 * c + 2] = vo.z; wo_[4 * c + 3] = vo.w;
    }
  }
#pragma unroll
  for (int g4 = 0; g4 < 4; ++g4) {
    int row = u + 256 * g4;
#pragma unroll
    for (int uu = 0; uu < 4; ++uu) {
      h2 t2 = {(f16)w_ih[row * NC + 8 * half + 2 * uu],
               (f16)w_ih[row * NC + 8 * half + 2 * uu + 1]};
      wih[g4][uu] = t2;
    }
  }
  const float K = 1.f / 127.f;
  float sci = scales[u] * K;
  float scf = scales[256 + u] * K;
  float scg = scales[512 + u] * K;
  float sco = scales[768 + u] * K;
  // biases only in half 0 (added exactly once per gate sum)
  float bi_ = half ? 0.f : b_ih[u] + b_hh[u];
  float bf_ = half ? 0.f : b_ih[256 + u] + b_hh[256 + u];
  float bg_ = half ? 0.f : b_ih[512 + u] + b_hh[512 + u];
  float bo_ = half ? 0.f : b_ih[768 + u] + b_hh[768 + u];

  // zero h copies (both phases), stage x chunk 0
  for (int e = t; e < 2 * HPHASE; e += 512) hq8[e] = 0;
#pragma unroll
  for (int r = 0; r < 2; ++r) {
    int e = t + 512 * r;  // 0..1023 over (c, tt)
    int cc = e >> 6, tt = e & 63;
    xs[tt][cc] = (f16)x[(size_t)(b * NC + cc) * NT + tt];
  }
  __syncthreads();

  // ---------------- recurrence ----------------
  float c_ = 0.f, h_last = 0.f;
  const int rdoff = 400 * half;      // copy(half) + k-range offset, 16B-aligned
  const int wroff = 272 * half + u;  // byte slot in copy(half)

#pragma unroll 1
  for (int s = 0; s < NT; ++s) {
    const int p = s & 1;
    const int4* hrd = (const int4*)(hq8 + p * HPHASE + rdoff);

    float fi = bi_, ff = bf_, fg2 = bg_, fo = bo_;
    // x projection: this half's 8 channels = 4 f16 pairs (f32 acc)
    {
      h8 xv = *(const h8*)&xs[s & 63][8 * half];
#pragma unroll
      for (int uu = 0; uu < 4; ++uu) {
        h2 xp = {xv[2 * uu], xv[2 * uu + 1]};
        fi = fdot2(xp, wih[0][uu], fi);
        ff = fdot2(xp, wih[1][uu], ff);
        fg2 = fdot2(xp, wih[2][uu], fg2);
        fo = fdot2(xp, wih[3][uu], fo);
      }
    }

    // recurrent dots over this thread's 128-wide k-half (i8 x i8 -> i32)
    int ai = 0, af = 0, ag = 0, ao = 0;
#pragma unroll
    for (int c = 0; c < 8; ++c) {
      int4 hv = hrd[c];  // 2 bank-disjoint broadcast addrs/wave
      ai = sdot4(hv.x, wi_[4 * c + 0], ai); ai = sdot4(hv.y, wi_[4 * c + 1], ai);
      ai = sdot4(hv.z, wi_[4 * c + 2], ai); ai = sdot4(hv.w, wi_[4 * c + 3], ai);
      af = sdot4(hv.x, wf_[4 * c + 0], af); af = sdot4(hv.y, wf_[4 * c + 1], af);
      af = sdot4(hv.z, wf_[4 * c + 2], af); af = sdot4(hv.w, wf_[4 * c + 3], af);
      ag = sdot4(hv.x, wg_[4 * c + 0], ag); ag = sdot4(hv.y, wg_[4 * c + 1], ag);
      ag = sdot4(hv.z, wg_[4 * c + 2], ag); ag = sdot4(hv.w, wg_[4 * c + 3], ag);
      ao = sdot4(hv.x, wo_[4 * c + 0], ao); ao = sdot4(hv.y, wo_[4 * c + 1], ao);
      ao = sdot4(hv.z, wo_[4 * c + 2], ao); ao = sdot4(hv.w, wo_[4 * c + 3], ao);
    }

    // dequantize per lane, then pair-reduce (lanes 2u,2u+1) via DPP;
    // result bit-identical on both lanes.
    float vi = fi + (float)ai * sci;
    float vf = ff + (float)af * scf;
    float vg = fg2 + (float)ag * scg;
    float vo = fo + (float)ao * sco;
    vi += pairswap(vi); vf += pairswap(vf); vg += pairswap(vg); vo += pairswap(vo);

    float ig = sigm(vi);
    float fgate = sigm(vf);
    float gv = tanh_(vg);
    float og = sigm(vo);
    c_ = fgate * c_ + ig * gv;
    float hh = og * tanh_(c_);
    h_last = hh;
    // quantize h (|hh| < 1); each lane updates its own copy(half)
    hq8[(1 - p) * HPHASE + wroff] = (int8_t)(int)rintf(hh * 127.f);

    // restage x every 64 steps (extra barrier protects WAR on xs)
    if ((s & 63) == 63 && s != NT - 1) {
      __syncthreads();
#pragma unroll
      for (int r = 0; r < 2; ++r) {
        int e = t + 512 * r;
        int cc = e >> 6, tt = e & 63;
        xs[tt][cc] = (f16)x[(size_t)(b * NC + cc) * NT + (s + 1) + tt];
      }
    }
    __syncthreads();
  }

  // ---------------- head: logits + log_softmax ----------------
  if (!half) hT[u] = h_last;
  __syncthreads();
  if (t < NO) {
    float acc = b_out[t];
    for (int k = 0; k < NH; ++k) acc += hT[k] * w_out[t * NH + k];
    lg[t] = acc;
  }
  __syncthreads();
  if (t == 0) {
    float m = lg[0];
    for (int o = 1; o < NO; ++o) m = fmaxf(m, lg[o]);
    float ssum = 0.f;
    for (int o = 0; o < NO; ++o) ssum += __expf(lg[o] - m);
    float lse = m + __logf(ssum);
    for (int o = 0; o < NO; ++o) out[b * NO + o] = lg[o] - lse;
  }
}

extern "C" void kernel_launch(void* const* d_in, const int* in_sizes, int n_in,
                              void* d_out, int out_size, void* d_ws, size_t ws_size,
                              hipStream_t stream) {
  const float* x    = (const float*)d_in[0];
  const float* wih  = (const float*)d_in[1];
  const float* whh  = (const float*)d_in[2];
  const float* bih  = (const float*)d_in[3];
  const float* bhh  = (const float*)d_in[4];
  const float* wout = (const float*)d_in[5];
  const float* bout = (const float*)d_in[6];
  float* out = (float*)d_out;
  int8_t* wq = (int8_t*)d_ws;                       // 256 KB i8 w_hh
  float* scales = (float*)((char*)d_ws + NG * NH);  // 4 KB row scales

  hipLaunchKernelGGL(prepack_whh_i8, dim3(NG), dim3(NH), 0, stream, whh, wq, scales);
  hipLaunchKernelGGL(lstm_main, dim3(NB), dim3(512), 0, stream,
                     x, wih, bih, bhh, wout, bout, wq, scales, out);
}